// Round 3
// baseline (14984.212 us; speedup 1.0000x reference)
//
#include <hip/hip_runtime.h>
#include <stdint.h>

// RNNPPO: LSTM(512 steps) + ragged pack + 2x MLP heads. DTYPE-ROBUST:
// a sniff kernel detects whether float tensors are fp32 or bf16 (mode flag in
// ws), a conversion pass normalizes all tensors to bf16 workspace buffers,
// and the output is written as fp32 or bf16 per mode.
//
//  - persistent LSTM kernel: 8 batch-groups x 16 col-WGs = 128 WGs, block 512
//    (wave = gate*2 + colhalf). W_hh/W_ih fragments register-resident (96 VGPR).
//    x-part MFMAs issued before the per-step spin (sync-shadow prefetch).
//    Cross-WG h exchange via global parity buffer + per-step agent-scope flags.
//  - head GEMMs: 128x128 MFMA tiles, BK=32, global_load_lds width 16, chunked
//    over rows to bound workspace (~73 MB fixed + adaptive chunks).

#define T_STEPS 512
#define BATCH   128
#define DDIM    256
#define HDIM    512

typedef __attribute__((ext_vector_type(8))) short bf16x8;
typedef __attribute__((ext_vector_type(4))) float f32x4;
typedef unsigned short u16;
typedef unsigned int   u32;

__device__ __forceinline__ u16 f2bf(float x){
  u32 u = __builtin_bit_cast(u32, x);
  u32 r = u + 0x7fffu + ((u >> 16) & 1u);
  return (u16)(r >> 16);
}
__device__ __forceinline__ float bf2f(u16 h){
  u32 u = ((u32)h) << 16;
  return __builtin_bit_cast(float, u);
}
__device__ __forceinline__ float sigm(float x){ return 1.f/(1.f + __expf(-x)); }
__device__ __forceinline__ float tanh_f(float x){ return 1.f - 2.f/(1.f + __expf(2.f*x)); }

__device__ __forceinline__ void async_ld16(const void* g, void* l){
  __builtin_amdgcn_global_load_lds(
      (const __attribute__((address_space(1))) u32*)g,
      (__attribute__((address_space(3))) u32*)l, 16, 0, 0);
}

// ---------------- dtype sniff ----------------
// Interprets b_ih's even-indexed u16s as bf16. bf16 data -> sane magnitudes;
// fp32 data -> those u16s are float low-mantissa bits -> wild exponents.
__global__ void sniff_kernel(const u16* __restrict__ b, int* __restrict__ mode){
  if (threadIdx.x == 0){
    int bad = 0;
    for (int i = 0; i < 64; i++){
      u16 x = b[2*i];
      int e = (x >> 7) & 0xFF;         // bf16 exponent
      if (e < 0x60 || e > 0x85) bad++; // outside ~[2^-31, 2^6]
    }
    *mode = (bad > 16) ? 1 : 0;        // 1 = fp32 inputs, 0 = bf16 inputs
  }
}

// ---------------- convert anything -> bf16 ----------------
__global__ void cvt_kernel(const void* __restrict__ src, u16* __restrict__ dst,
                           int n, const int* __restrict__ mode){
  int i0 = (blockIdx.x*blockDim.x + threadIdx.x) * 8;
  if (i0 >= n) return;
  int m = *mode;
  if (m){
    const float* s = (const float*)src;
    if (i0 + 8 <= n){
      float4 a = *(const float4*)(s + i0);
      float4 b = *(const float4*)(s + i0 + 4);
      ushort4 oa, ob;
      oa.x=f2bf(a.x); oa.y=f2bf(a.y); oa.z=f2bf(a.z); oa.w=f2bf(a.w);
      ob.x=f2bf(b.x); ob.y=f2bf(b.y); ob.z=f2bf(b.z); ob.w=f2bf(b.w);
      *(ushort4*)(dst + i0) = oa;
      *(ushort4*)(dst + i0 + 4) = ob;
    } else {
      for (int i = i0; i < n; i++) dst[i] = f2bf(s[i]);
    }
  } else {
    const u16* s = (const u16*)src;
    if (i0 + 8 <= n){
      *(ushort4*)(dst + i0)     = *(const ushort4*)(s + i0);
      *(ushort4*)(dst + i0 + 4) = *(const ushort4*)(s + i0 + 4);
    } else {
      for (int i = i0; i < n; i++) dst[i] = s[i];
    }
  }
}

// ---------------- prep ----------------
__global__ void scan_kernel(const int* __restrict__ lens, int* __restrict__ off){
  if (threadIdx.x == 0){
    int a = 0;
    for (int b = 0; b < BATCH; b++){ off[b] = a; a += lens[b]; }
    off[BATCH] = a;
  }
}

// copy state rows (bf16) into packed inp[:,0:256]; 4 rows per 256-thr block
__global__ void pack_state_kernel(const u16* __restrict__ st_bf,
                                  const int* __restrict__ lens,
                                  const int* __restrict__ off,
                                  u16* __restrict__ inp){
  int r = blockIdx.x*4 + (threadIdx.x >> 6);   // dense row t*BATCH+b
  int lane = threadIdx.x & 63;
  int b = r & (BATCH-1), t = r >> 7;
  if (t >= lens[b]) return;
  long row = (long)off[b] + t;
  ushort4 v = ((const ushort4*)(st_bf + (long)r*DDIM))[lane];
  ((ushort4*)(inp + row*768))[lane] = v;
}

__global__ void zero_out_kernel(void* __restrict__ out, int n,
                                const int* __restrict__ mode){
  int i = blockIdx.x*blockDim.x + threadIdx.x;
  if (i >= n) return;
  if (*mode) ((float*)out)[i] = 0.f; else ((u16*)out)[i] = 0;
}

// ---------------- LSTM recurrence ----------------
__global__ __launch_bounds__(512, 2) void lstm_kernel(
    const u16* __restrict__ Whh, const u16* __restrict__ Wih,
    const u16* __restrict__ bih, const u16* __restrict__ bhh,
    const u16* __restrict__ cell0,
    const u16* __restrict__ state,
    u16* hbuf,                              // [2][BATCH*HDIM] (no restrict!)
    u16* __restrict__ inp,                  // [Np128*768]
    const int* __restrict__ off, const int* __restrict__ lens,
    int* flags)                             // [8*T_STEPS]
{
  const int tid  = threadIdx.x;
  const int wave = tid >> 6;
  const int lane = tid & 63;
  const int g    = blockIdx.x >> 4;     // batch group 0..7 (16 batches each)
  const int s    = blockIdx.x & 15;     // col-WG 0..15 (32 h-cols each)
  const int Sb   = s * 32;
  const int gate = wave >> 1;           // 0..3 (i,f,g,o)
  const int hf   = wave & 1;            // column half
  const int q    = lane >> 4;
  const int m16  = lane & 15;
  const int colg = gate*HDIM + Sb + hf*16 + m16;   // global gate column

  __shared__ float lds_acc[8][16][16];
  __shared__ float bias_l[128];
  __shared__ int   len_l[16];
  __shared__ int   off_l[16];

  if (tid < 128){
    int gt = tid >> 5, jx = tid & 31;
    int cg = gt*HDIM + Sb + jx;
    bias_l[tid] = bf2f(bih[cg]) + bf2f(bhh[cg]);
  }
  if (tid < 16){ len_l[tid] = lens[g*16 + tid]; off_l[tid] = off[g*16 + tid]; }

  // register-resident weight fragments (B operand: lane holds W[col][k], k=c*32+q*8+j)
  bf16x8 whh[16], wih[8];
  {
    const u16* wb = Whh + (long)colg*HDIM + q*8;
    #pragma unroll
    for (int c = 0; c < 16; c++) whh[c] = *(const bf16x8*)(wb + c*32);
    const u16* wb2 = Wih + (long)colg*DDIM + q*8;
    #pragma unroll
    for (int c = 0; c < 8; c++) wih[c] = *(const bf16x8*)(wb2 + c*32);
  }

  const int b_l = tid >> 5;    // epilogue ownership: (batch b_l, col j)
  const int j   = tid & 31;
  const int hx  = j >> 4;
  const int jj  = j & 15;
  float cval = bf2f(cell0[(g*16 + b_l)*HDIM + Sb + j]);

  __syncthreads();

  const int fbase = g * T_STEPS;

  for (int t = 0; t < T_STEPS; t++){
    f32x4 acc = {0.f, 0.f, 0.f, 0.f};
    // x-part: independent of h, issued before the spin (prefetch in sync shadow)
    {
      const u16* xb = state + ((long)(t*BATCH + g*16 + m16))*DDIM + q*8;
      #pragma unroll
      for (int c = 0; c < 8; c++){
        bf16x8 a = *(const bf16x8*)(xb + c*32);
        acc = __builtin_amdgcn_mfma_f32_16x16x32_bf16(a, wih[c], acc, 0, 0, 0);
      }
    }
    if (t > 0){
      if (tid == 0){
        while (__hip_atomic_load(&flags[fbase + t - 1], __ATOMIC_ACQUIRE,
                                 __HIP_MEMORY_SCOPE_AGENT) < 16)
          __builtin_amdgcn_s_sleep(1);
      }
      __syncthreads();
      asm volatile("" ::: "memory");   // no hoisting of h loads above the spin
    }
    // h-part
    {
      const u16* hb = hbuf + ((t & 1) ^ 1)*(BATCH*HDIM) + (g*16 + m16)*HDIM + q*8;
      #pragma unroll
      for (int c = 0; c < 16; c++){
        bf16x8 a = *(const bf16x8*)(hb + c*32);
        acc = __builtin_amdgcn_mfma_f32_16x16x32_bf16(a, whh[c], acc, 0, 0, 0);
      }
    }
    // gate exchange through LDS (C layout: row(batch)=q*4+r, col=lane&15)
    #pragma unroll
    for (int r = 0; r < 4; r++) lds_acc[wave][q*4 + r][m16] = acc[r];
    __syncthreads();

    float iv = lds_acc[0 + hx][b_l][jj] + bias_l[ 0 + j];
    float fv = lds_acc[2 + hx][b_l][jj] + bias_l[32 + j];
    float gv = lds_acc[4 + hx][b_l][jj] + bias_l[64 + j];
    float ov = lds_acc[6 + hx][b_l][jj] + bias_l[96 + j];
    cval = sigm(fv)*cval + sigm(iv)*tanh_f(gv);
    float hv = sigm(ov)*tanh_f(cval);
    u16 hb16 = f2bf(hv);
    hbuf[(t & 1)*(BATCH*HDIM) + (g*16 + b_l)*HDIM + Sb + j] = hb16;
    __threadfence();       // make h stores visible at agent scope
    __syncthreads();       // all threads' stores fenced before the signal
    if (tid == 0)
      __hip_atomic_fetch_add(&flags[fbase + t], 1, __ATOMIC_RELEASE,
                             __HIP_MEMORY_SCOPE_AGENT);
    // packed-h store is off the critical path (consumed only after kernel end)
    if (t < len_l[b_l])
      inp[((long)(off_l[b_l] + t))*768 + DDIM + Sb + j] = hb16;
  }
}

// ---------------- MLP GEMM: C = relu(A @ W^T + bias), bf16 in/out ----------------
__global__ __launch_bounds__(256) void gemm_kernel(
    const u16* __restrict__ A,   // [rows x K]
    const u16* __restrict__ W,   // [512 x K]
    const u16* __restrict__ bias,
    u16* __restrict__ C,         // [rows x 512]
    int K)
{
  __shared__ u16 As[128*32];
  __shared__ u16 Bs[128*32];
  const int tid = threadIdx.x, wave = tid >> 6, lane = tid & 63;
  const int bm = blockIdx.x * 128;
  const int bn = blockIdx.y * 128;
  const int wr = (wave >> 1) * 64;
  const int wc = (wave & 1) * 64;
  const int q = lane >> 4, m16 = lane & 15;
  const int rsub = lane >> 2;          // 0..15
  const int ksub = (lane & 3) * 8;     // elems

  f32x4 acc[4][4] = {};

  for (int k0 = 0; k0 < K; k0 += 32){
    __syncthreads();
    #pragma unroll
    for (int i = 0; i < 2; i++){
      int rr = (i*4 + wave) * 16 + rsub;
      async_ld16(A + (long)(bm + rr)*K + k0 + ksub, As + (i*4 + wave)*512);
      async_ld16(W + (long)(bn + rr)*K + k0 + ksub, Bs + (i*4 + wave)*512);
    }
    __syncthreads();
    bf16x8 af[4], bfr[4];
    #pragma unroll
    for (int r = 0; r < 4; r++) af[r]  = *(const bf16x8*)(As + (wr + r*16 + m16)*32 + q*8);
    #pragma unroll
    for (int c = 0; c < 4; c++) bfr[c] = *(const bf16x8*)(Bs + (wc + c*16 + m16)*32 + q*8);
    #pragma unroll
    for (int r = 0; r < 4; r++)
      #pragma unroll
      for (int c = 0; c < 4; c++)
        acc[r][c] = __builtin_amdgcn_mfma_f32_16x16x32_bf16(af[r], bfr[c], acc[r][c], 0, 0, 0);
  }
  #pragma unroll
  for (int c = 0; c < 4; c++){
    int col = bn + wc + c*16 + m16;
    float bv = bf2f(bias[col]);
    #pragma unroll
    for (int r = 0; r < 4; r++){
      #pragma unroll
      for (int x = 0; x < 4; x++){
        int row = bm + wr + r*16 + q*4 + x;
        float v = acc[r][c][x] + bv;
        v = fmaxf(v, 0.f);
        C[(long)row*512 + col] = f2bf(v);
      }
    }
  }
}

// ---------------- final fused layer: actor(3, tanh) + critic(1) ----------------
__global__ void final_kernel(
    const u16* __restrict__ a2, const u16* __restrict__ c2,
    const u16* __restrict__ aw2, const u16* __restrict__ ab2,
    const u16* __restrict__ cw2, const u16* __restrict__ cb2,
    void* __restrict__ out, int base, int nvalid, int N,
    const int* __restrict__ mode)
{
  int lw = (blockIdx.x * blockDim.x + threadIdx.x) >> 6;   // local row
  int lane = threadIdx.x & 63;
  if (lw >= nvalid) return;
  int k = lane * 8;
  bf16x8 av = *(const bf16x8*)(a2 + (long)lw*512 + k);
  bf16x8 cv = *(const bf16x8*)(c2 + (long)lw*512 + k);
  bf16x8 w0 = *(const bf16x8*)(aw2 + k);
  bf16x8 w1 = *(const bf16x8*)(aw2 + 512 + k);
  bf16x8 w2 = *(const bf16x8*)(aw2 + 1024 + k);
  bf16x8 wc = *(const bf16x8*)(cw2 + k);
  float d0=0.f, d1=0.f, d2=0.f, dc=0.f;
  #pragma unroll
  for (int x = 0; x < 8; x++){
    float a  = bf2f((u16)av[x]);
    float cc = bf2f((u16)cv[x]);
    d0 += a  * bf2f((u16)w0[x]);
    d1 += a  * bf2f((u16)w1[x]);
    d2 += a  * bf2f((u16)w2[x]);
    dc += cc * bf2f((u16)wc[x]);
  }
  #pragma unroll
  for (int o = 32; o > 0; o >>= 1){
    d0 += __shfl_down(d0, o);
    d1 += __shfl_down(d1, o);
    d2 += __shfl_down(d2, o);
    dc += __shfl_down(dc, o);
  }
  if (lane == 0){
    int gr = base + lw;
    float r0 = tanh_f(d0 + bf2f(ab2[0]));
    float r1 = tanh_f(d1 + bf2f(ab2[1]));
    float r2 = tanh_f(d2 + bf2f(ab2[2]));
    float rc = dc + bf2f(cb2[0]);
    if (*mode){
      float* o = (float*)out;
      o[(long)gr*3 + 0] = r0; o[(long)gr*3 + 1] = r1; o[(long)gr*3 + 2] = r2;
      o[(long)3*N + gr] = rc;
    } else {
      u16* o = (u16*)out;
      o[(long)gr*3 + 0] = f2bf(r0); o[(long)gr*3 + 1] = f2bf(r1);
      o[(long)gr*3 + 2] = f2bf(r2);
      o[(long)3*N + gr] = f2bf(rc);
    }
  }
}

extern "C" void kernel_launch(void* const* d_in, const int* in_sizes, int n_in,
                              void* d_out, int out_size, void* d_ws, size_t ws_size,
                              hipStream_t stream)
{
  const void* state = d_in[0];
  const void* h0    = d_in[1];
  const void* c0    = d_in[2];
  const int*  lens  = (const int*)d_in[3];
  const void* Wih   = d_in[4];
  const void* Whh   = d_in[5];
  const void* bih   = d_in[6];
  const void* bhh   = d_in[7];
  const void* aw0   = d_in[8];
  const void* ab0   = d_in[9];
  const void* aw1   = d_in[10];
  const void* ab1   = d_in[11];
  const void* aw2   = d_in[12];
  const void* ab2   = d_in[13];
  const void* cw0   = d_in[14];
  const void* cb0   = d_in[15];
  const void* cw1   = d_in[16];
  const void* cb1   = d_in[17];
  const void* cw2   = d_in[18];
  const void* cb2   = d_in[19];
  (void)in_sizes; (void)n_in;

  const int N = out_size / 4;             // actor 3N + critic N
  const int Np128 = (N + 127) & ~127;

  char* ws = (char*)d_ws;
  size_t cur = 0;
  auto alloc = [&](size_t bytes)->char*{
    char* p = ws + cur; cur += (bytes + 255) & ~(size_t)255; return p;
  };
  int* mode   = (int*)alloc(4);
  int* off    = (int*)alloc(129*4);
  int* flags  = (int*)alloc(8*T_STEPS*4);
  u16* hbuf   = (u16*)alloc((size_t)2*BATCH*HDIM*2);
  u16* cbf    = (u16*)alloc((size_t)BATCH*HDIM*2);
  u16* wih_b  = (u16*)alloc((size_t)2048*256*2);
  u16* whh_b  = (u16*)alloc((size_t)2048*512*2);
  u16* bih_b  = (u16*)alloc(2048*2);
  u16* bhh_b  = (u16*)alloc(2048*2);
  u16* st_bf  = (u16*)alloc((size_t)T_STEPS*BATCH*DDIM*2);
  u16* wa0    = (u16*)alloc((size_t)512*768*2);
  u16* ba0    = (u16*)alloc(512*2);
  u16* wa1    = (u16*)alloc((size_t)512*512*2);
  u16* ba1    = (u16*)alloc(512*2);
  u16* wa2    = (u16*)alloc(1536*2);
  u16* ba2    = (u16*)alloc(256*2);
  u16* wc0    = (u16*)alloc((size_t)512*768*2);
  u16* bc0    = (u16*)alloc(512*2);
  u16* wc1    = (u16*)alloc((size_t)512*512*2);
  u16* bc1    = (u16*)alloc(512*2);
  u16* wc2    = (u16*)alloc(512*2);
  u16* bc2    = (u16*)alloc(256*2);
  u16* inp    = (u16*)alloc((size_t)Np128*768*2);

  sniff_kernel<<<1, 64, 0, stream>>>((const u16*)bih, mode);

  if (cur > ws_size){   // workspace too small: clean diagnostic failure
    zero_out_kernel<<<(out_size + 255)/256, 256, 0, stream>>>(d_out, out_size, mode);
    return;
  }
  size_t rem = ws_size - cur;
  long CH_l = (long)((rem / 3) / (512*2)) & ~127L;
  int CH = (int)(CH_l > 8192 ? 8192 : CH_l);
  if (CH < 128){
    zero_out_kernel<<<(out_size + 255)/256, 256, 0, stream>>>(d_out, out_size, mode);
    return;
  }
  u16* bufA = (u16*)alloc((size_t)CH*512*2);
  u16* bufB = (u16*)alloc((size_t)CH*512*2);
  u16* bufC = (u16*)alloc((size_t)CH*512*2);

  auto cvt = [&](const void* src, u16* dst, int n){
    int thr = (n + 7) / 8;
    cvt_kernel<<<(thr + 255)/256, 256, 0, stream>>>(src, dst, n, mode);
  };
  cvt(Wih, wih_b, 2048*256);
  cvt(Whh, whh_b, 2048*512);
  cvt(bih, bih_b, 2048);
  cvt(bhh, bhh_b, 2048);
  cvt(h0,  hbuf + BATCH*HDIM, BATCH*HDIM);   // parity 1 = h_{-1}
  cvt(c0,  cbf, BATCH*HDIM);
  cvt(state, st_bf, T_STEPS*BATCH*DDIM);
  cvt(aw0, wa0, 512*768);  cvt(ab0, ba0, 512);
  cvt(aw1, wa1, 512*512);  cvt(ab1, ba1, 512);
  cvt(aw2, wa2, 1536);     cvt(ab2, ba2, 3);
  cvt(cw0, wc0, 512*768);  cvt(cb0, bc0, 512);
  cvt(cw1, wc1, 512*512);  cvt(cb1, bc1, 512);
  cvt(cw2, wc2, 512);      cvt(cb2, bc2, 1);

  hipMemsetAsync(flags, 0, 8*T_STEPS*4, stream);
  scan_kernel<<<1, 64, 0, stream>>>(lens, off);
  pack_state_kernel<<<(T_STEPS*BATCH)/4, 256, 0, stream>>>(st_bf, lens, off, inp);

  lstm_kernel<<<128, 512, 0, stream>>>(whh_b, wih_b, bih_b, bhh_b, cbf, st_bf,
                                       hbuf, inp, off, lens, flags);

  for (int cs = 0; cs < Np128; cs += CH){
    int rows = (Np128 - cs) < CH ? (Np128 - cs) : CH;
    int gm = rows / 128;
    dim3 gg(gm, 4);
    gemm_kernel<<<gg, 256, 0, stream>>>(inp + (long)cs*768, wa0, ba0, bufA, 768);
    gemm_kernel<<<gg, 256, 0, stream>>>(bufA,               wa1, ba1, bufB, 512);
    gemm_kernel<<<gg, 256, 0, stream>>>(inp + (long)cs*768, wc0, bc0, bufA, 768);
    gemm_kernel<<<gg, 256, 0, stream>>>(bufA,               wc1, bc1, bufC, 512);
    int nvalid = (N - cs) < rows ? (N - cs) : rows;
    if (nvalid > 0)
      final_kernel<<<(nvalid + 3)/4, 256, 0, stream>>>(bufB, bufC, wa2, ba2,
                                                       wc2, bc2, d_out, cs,
                                                       nvalid, N, mode);
  }
}

// Round 5
// 5936.363 us; speedup vs baseline: 2.5241x; 2.5241x over previous
//
#include <hip/hip_runtime.h>
#include <stdint.h>

// RNNPPO: LSTM(512 steps) + ragged pack + 2x MLP heads. DTYPE-ROBUST:
// a sniff kernel detects whether float tensors are fp32 or bf16 (mode flag in
// ws), a conversion pass normalizes all tensors to bf16 workspace buffers,
// and the output is written as fp32 or bf16 per mode.
//
// R5: cross-WG h exchange via COMPILER-VISIBLE device-scope atomics
// (relaxed agent __hip_atomic_load/store -> sc-coherent LLC traffic, tracked
// by the waitcnt pass) instead of R4's raw inline asm (aborted: asm loads are
// invisible to SIInsertWaitcnts / regalloc). No threadfence anywhere ->
// no per-step buffer_wbl2/buffer_inv (R3: 28us/step, FETCH 398MB L2 thrash).
// Spin is bounded so a protocol wedge degrades to wrong-answer, not a hang.
//
//  - persistent LSTM kernel: 8 batch-groups x 16 col-WGs = 128 WGs, block 512
//    (wave = gate*2 + colhalf). W_hh/W_ih fragments register-resident.
//    x-part MFMAs issued before the per-step spin (sync-shadow prefetch).
//  - head GEMMs: 128x128 MFMA tiles, BK=32, global_load_lds width 16, chunked.

#define T_STEPS 512
#define BATCH   128
#define DDIM    256
#define HDIM    512

typedef __attribute__((ext_vector_type(8))) short bf16x8;
typedef __attribute__((ext_vector_type(4))) float f32x4;
typedef __attribute__((ext_vector_type(2))) unsigned long long u64x2;
typedef unsigned short u16;
typedef unsigned int   u32;
typedef unsigned long long u64;

__device__ __forceinline__ u16 f2bf(float x){
  u32 u = __builtin_bit_cast(u32, x);
  u32 r = u + 0x7fffu + ((u >> 16) & 1u);
  return (u16)(r >> 16);
}
__device__ __forceinline__ float bf2f(u16 h){
  u32 u = ((u32)h) << 16;
  return __builtin_bit_cast(float, u);
}
__device__ __forceinline__ float sigm(float x){ return 1.f/(1.f + __expf(-x)); }
__device__ __forceinline__ float tanh_f(float x){ return 1.f - 2.f/(1.f + __expf(2.f*x)); }

__device__ __forceinline__ void async_ld16(const void* g, void* l){
  __builtin_amdgcn_global_load_lds(
      (const __attribute__((address_space(1))) u32*)g,
      (__attribute__((address_space(3))) u32*)l, 16, 0, 0);
}

// ---------------- dtype sniff ----------------
__global__ void sniff_kernel(const u16* __restrict__ b, int* __restrict__ mode){
  if (threadIdx.x == 0){
    int bad = 0;
    for (int i = 0; i < 64; i++){
      u16 x = b[2*i];
      int e = (x >> 7) & 0xFF;         // bf16 exponent
      if (e < 0x60 || e > 0x85) bad++; // outside ~[2^-31, 2^6]
    }
    *mode = (bad > 16) ? 1 : 0;        // 1 = fp32 inputs, 0 = bf16 inputs
  }
}

// ---------------- convert anything -> bf16 ----------------
__global__ void cvt_kernel(const void* __restrict__ src, u16* __restrict__ dst,
                           int n, const int* __restrict__ mode){
  int i0 = (blockIdx.x*blockDim.x + threadIdx.x) * 8;
  if (i0 >= n) return;
  int m = *mode;
  if (m){
    const float* s = (const float*)src;
    if (i0 + 8 <= n){
      float4 a = *(const float4*)(s + i0);
      float4 b = *(const float4*)(s + i0 + 4);
      ushort4 oa, ob;
      oa.x=f2bf(a.x); oa.y=f2bf(a.y); oa.z=f2bf(a.z); oa.w=f2bf(a.w);
      ob.x=f2bf(b.x); ob.y=f2bf(b.y); ob.z=f2bf(b.z); ob.w=f2bf(b.w);
      *(ushort4*)(dst + i0) = oa;
      *(ushort4*)(dst + i0 + 4) = ob;
    } else {
      for (int i = i0; i < n; i++) dst[i] = f2bf(s[i]);
    }
  } else {
    const u16* s = (const u16*)src;
    if (i0 + 8 <= n){
      *(ushort4*)(dst + i0)     = *(const ushort4*)(s + i0);
      *(ushort4*)(dst + i0 + 4) = *(const ushort4*)(s + i0 + 4);
    } else {
      for (int i = i0; i < n; i++) dst[i] = s[i];
    }
  }
}

// ---------------- prep ----------------
__global__ void scan_kernel(const int* __restrict__ lens, int* __restrict__ off){
  if (threadIdx.x == 0){
    int a = 0;
    for (int b = 0; b < BATCH; b++){ off[b] = a; a += lens[b]; }
    off[BATCH] = a;
  }
}

__global__ void pack_state_kernel(const u16* __restrict__ st_bf,
                                  const int* __restrict__ lens,
                                  const int* __restrict__ off,
                                  u16* __restrict__ inp){
  int r = blockIdx.x*4 + (threadIdx.x >> 6);   // dense row t*BATCH+b
  int lane = threadIdx.x & 63;
  int b = r & (BATCH-1), t = r >> 7;
  if (t >= lens[b]) return;
  long row = (long)off[b] + t;
  ushort4 v = ((const ushort4*)(st_bf + (long)r*DDIM))[lane];
  ((ushort4*)(inp + row*768))[lane] = v;
}

__global__ void zero_out_kernel(void* __restrict__ out, int n,
                                const int* __restrict__ mode){
  int i = blockIdx.x*blockDim.x + threadIdx.x;
  if (i >= n) return;
  if (*mode) ((float*)out)[i] = 0.f; else ((u16*)out)[i] = 0;
}

// ---------------- LSTM recurrence ----------------
__global__ __launch_bounds__(512, 2) void lstm_kernel(
    const u16* __restrict__ Whh, const u16* __restrict__ Wih,
    const u16* __restrict__ bih, const u16* __restrict__ bhh,
    const u16* __restrict__ cell0,
    const u16* __restrict__ state,
    u16* hbuf,                              // [2][BATCH*HDIM]
    u16* __restrict__ inp,                  // [Np128*768]
    const int* __restrict__ off, const int* __restrict__ lens,
    int* flags)                             // [8*T_STEPS]
{
  const int tid  = threadIdx.x;
  const int wave = tid >> 6;
  const int lane = tid & 63;
  const int g    = blockIdx.x >> 4;     // batch group 0..7 (16 batches each)
  const int s    = blockIdx.x & 15;     // col-WG 0..15 (32 h-cols each)
  const int Sb   = s * 32;
  const int gate = wave >> 1;           // 0..3 (i,f,g,o)
  const int hf   = wave & 1;            // column half
  const int q    = lane >> 4;
  const int m16  = lane & 15;
  const int colg = gate*HDIM + Sb + hf*16 + m16;   // global gate column

  __shared__ float lds_acc[8][16][16];
  __shared__ float bias_l[128];
  __shared__ int   len_l[16];
  __shared__ int   off_l[16];

  if (tid < 128){
    int gt = tid >> 5, jx = tid & 31;
    int cg = gt*HDIM + Sb + jx;
    bias_l[tid] = bf2f(bih[cg]) + bf2f(bhh[cg]);
  }
  if (tid < 16){ len_l[tid] = lens[g*16 + tid]; off_l[tid] = off[g*16 + tid]; }

  // register-resident weight fragments (B operand: lane holds W[col][k])
  bf16x8 whh[16], wih[8];
  {
    const u16* wb = Whh + (long)colg*HDIM + q*8;
    #pragma unroll
    for (int c = 0; c < 16; c++) whh[c] = *(const bf16x8*)(wb + c*32);
    const u16* wb2 = Wih + (long)colg*DDIM + q*8;
    #pragma unroll
    for (int c = 0; c < 8; c++) wih[c] = *(const bf16x8*)(wb2 + c*32);
  }

  const int b_l = tid >> 5;    // epilogue ownership: (batch b_l, col j)
  const int j   = tid & 31;
  const int hx  = j >> 4;
  const int jj  = j & 15;
  float cval = bf2f(cell0[(g*16 + b_l)*HDIM + Sb + j]);

  __syncthreads();

  const int fbase = g * T_STEPS;

  for (int t = 0; t < T_STEPS; t++){
    f32x4 acc = {0.f, 0.f, 0.f, 0.f};
    // x-part: independent of h, issued before the spin (sync-shadow prefetch)
    {
      const u16* xb = state + ((long)(t*BATCH + g*16 + m16))*DDIM + q*8;
      #pragma unroll
      for (int c = 0; c < 8; c++){
        bf16x8 a = *(const bf16x8*)(xb + c*32);
        acc = __builtin_amdgcn_mfma_f32_16x16x32_bf16(a, wih[c], acc, 0, 0, 0);
      }
    }
    // per-wave spin: lane 0 polls a device-scope atomic (relaxed: no cache
    // maintenance; atomics read the coherent LLC directly). Bounded so a
    // protocol wedge degrades to wrong results instead of a watchdog abort.
    if (t > 0){
      if (lane == 0){
        int spins = 0;
        while (__hip_atomic_load(&flags[fbase + t - 1], __ATOMIC_RELAXED,
                                 __HIP_MEMORY_SCOPE_AGENT) < 16){
          if (++spins > (1 << 16)) break;
          __builtin_amdgcn_s_sleep(1);
        }
      }
      asm volatile("" ::: "memory");   // compile-time: no hoisting above spin
    }
    // h-part: device-scope relaxed atomic loads (sc-coherent, LLC-served,
    // fully tracked by the compiler's waitcnt pass)
    {
      const u16* hb = hbuf + ((t & 1) ^ 1)*(BATCH*HDIM) + (g*16 + m16)*HDIM + q*8;
      u64 lo[16], hi[16];
      #pragma unroll
      for (int c = 0; c < 16; c++){
        lo[c] = __hip_atomic_load((const u64*)(hb + c*32),
                                  __ATOMIC_RELAXED, __HIP_MEMORY_SCOPE_AGENT);
        hi[c] = __hip_atomic_load((const u64*)(hb + c*32 + 4),
                                  __ATOMIC_RELAXED, __HIP_MEMORY_SCOPE_AGENT);
      }
      #pragma unroll
      for (int c = 0; c < 16; c++){
        u64x2 v; v[0] = lo[c]; v[1] = hi[c];
        bf16x8 a = __builtin_bit_cast(bf16x8, v);
        acc = __builtin_amdgcn_mfma_f32_16x16x32_bf16(a, whh[c], acc, 0, 0, 0);
      }
    }
    // gate exchange through LDS (C layout: row(batch)=q*4+r, col=lane&15)
    #pragma unroll
    for (int r = 0; r < 4; r++) lds_acc[wave][q*4 + r][m16] = acc[r];
    __syncthreads();

    float iv = lds_acc[0 + hx][b_l][jj] + bias_l[ 0 + j];
    float fv = lds_acc[2 + hx][b_l][jj] + bias_l[32 + j];
    float gv = lds_acc[4 + hx][b_l][jj] + bias_l[64 + j];
    float ov = lds_acc[6 + hx][b_l][jj] + bias_l[96 + j];
    cval = sigm(fv)*cval + sigm(iv)*tanh_f(gv);
    float hv = sigm(ov)*tanh_f(cval);
    u16 hb16 = f2bf(hv);
    // pair adjacent columns (j, j+1) and store u32 via device-scope relaxed
    // atomic (write-through to LLC; L2 never holds dirty h lines)
    int nb = __shfl_down((int)hb16, 1);
    if ((j & 1) == 0){
      size_t hidx = (size_t)(t & 1)*(BATCH*HDIM) + (g*16 + b_l)*HDIM + Sb + j;
      u32 pair = (u32)hb16 | ((u32)(u16)nb << 16);
      __hip_atomic_store((u32*)(hbuf + hidx), pair,
                         __ATOMIC_RELAXED, __HIP_MEMORY_SCOPE_AGENT);
    }
    __builtin_amdgcn_s_waitcnt(0);   // own store ack'd at LLC
    __syncthreads();                 // all threads' stores ack'd
    if (tid == 0)
      __hip_atomic_fetch_add(&flags[fbase + t], 1, __ATOMIC_RELAXED,
                             __HIP_MEMORY_SCOPE_AGENT);
    // packed-h store is off the critical path (consumed only after kernel end)
    if (t < len_l[b_l])
      inp[((long)(off_l[b_l] + t))*768 + DDIM + Sb + j] = hb16;
  }
}

// ---------------- MLP GEMM: C = relu(A @ W^T + bias), bf16 in/out ----------------
__global__ __launch_bounds__(256) void gemm_kernel(
    const u16* __restrict__ A,   // [rows x K]
    const u16* __restrict__ W,   // [512 x K]
    const u16* __restrict__ bias,
    u16* __restrict__ C,         // [rows x 512]
    int K)
{
  __shared__ u16 As[128*32];
  __shared__ u16 Bs[128*32];
  const int tid = threadIdx.x, wave = tid >> 6, lane = tid & 63;
  const int bm = blockIdx.x * 128;
  const int bn = blockIdx.y * 128;
  const int wr = (wave >> 1) * 64;
  const int wc = (wave & 1) * 64;
  const int q = lane >> 4, m16 = lane & 15;
  const int rsub = lane >> 2;          // 0..15
  const int ksub = (lane & 3) * 8;     // elems

  f32x4 acc[4][4] = {};

  for (int k0 = 0; k0 < K; k0 += 32){
    __syncthreads();
    #pragma unroll
    for (int i = 0; i < 2; i++){
      int rr = (i*4 + wave) * 16 + rsub;
      async_ld16(A + (long)(bm + rr)*K + k0 + ksub, As + (i*4 + wave)*512);
      async_ld16(W + (long)(bn + rr)*K + k0 + ksub, Bs + (i*4 + wave)*512);
    }
    __syncthreads();
    bf16x8 af[4], bfr[4];
    #pragma unroll
    for (int r = 0; r < 4; r++) af[r]  = *(const bf16x8*)(As + (wr + r*16 + m16)*32 + q*8);
    #pragma unroll
    for (int c = 0; c < 4; c++) bfr[c] = *(const bf16x8*)(Bs + (wc + c*16 + m16)*32 + q*8);
    #pragma unroll
    for (int r = 0; r < 4; r++)
      #pragma unroll
      for (int c = 0; c < 4; c++)
        acc[r][c] = __builtin_amdgcn_mfma_f32_16x16x32_bf16(af[r], bfr[c], acc[r][c], 0, 0, 0);
  }
  #pragma unroll
  for (int c = 0; c < 4; c++){
    int col = bn + wc + c*16 + m16;
    float bv = bf2f(bias[col]);
    #pragma unroll
    for (int r = 0; r < 4; r++){
      #pragma unroll
      for (int x = 0; x < 4; x++){
        int row = bm + wr + r*16 + q*4 + x;
        float v = acc[r][c][x] + bv;
        v = fmaxf(v, 0.f);
        C[(long)row*512 + col] = f2bf(v);
      }
    }
  }
}

// ---------------- final fused layer: actor(3, tanh) + critic(1) ----------------
__global__ void final_kernel(
    const u16* __restrict__ a2, const u16* __restrict__ c2,
    const u16* __restrict__ aw2, const u16* __restrict__ ab2,
    const u16* __restrict__ cw2, const u16* __restrict__ cb2,
    void* __restrict__ out, int base, int nvalid, int N,
    const int* __restrict__ mode)
{
  int lw = (blockIdx.x * blockDim.x + threadIdx.x) >> 6;   // local row
  int lane = threadIdx.x & 63;
  if (lw >= nvalid) return;
  int k = lane * 8;
  bf16x8 av = *(const bf16x8*)(a2 + (long)lw*512 + k);
  bf16x8 cv = *(const bf16x8*)(c2 + (long)lw*512 + k);
  bf16x8 w0 = *(const bf16x8*)(aw2 + k);
  bf16x8 w1 = *(const bf16x8*)(aw2 + 512 + k);
  bf16x8 w2 = *(const bf16x8*)(aw2 + 1024 + k);
  bf16x8 wc = *(const bf16x8*)(cw2 + k);
  float d0=0.f, d1=0.f, d2=0.f, dc=0.f;
  #pragma unroll
  for (int x = 0; x < 8; x++){
    float a  = bf2f((u16)av[x]);
    float cc = bf2f((u16)cv[x]);
    d0 += a  * bf2f((u16)w0[x]);
    d1 += a  * bf2f((u16)w1[x]);
    d2 += a  * bf2f((u16)w2[x]);
    dc += cc * bf2f((u16)wc[x]);
  }
  #pragma unroll
  for (int o = 32; o > 0; o >>= 1){
    d0 += __shfl_down(d0, o);
    d1 += __shfl_down(d1, o);
    d2 += __shfl_down(d2, o);
    dc += __shfl_down(dc, o);
  }
  if (lane == 0){
    int gr = base + lw;
    float r0 = tanh_f(d0 + bf2f(ab2[0]));
    float r1 = tanh_f(d1 + bf2f(ab2[1]));
    float r2 = tanh_f(d2 + bf2f(ab2[2]));
    float rc = dc + bf2f(cb2[0]);
    if (*mode){
      float* o = (float*)out;
      o[(long)gr*3 + 0] = r0; o[(long)gr*3 + 1] = r1; o[(long)gr*3 + 2] = r2;
      o[(long)3*N + gr] = rc;
    } else {
      u16* o = (u16*)out;
      o[(long)gr*3 + 0] = f2bf(r0); o[(long)gr*3 + 1] = f2bf(r1);
      o[(long)gr*3 + 2] = f2bf(r2);
      o[(long)3*N + gr] = f2bf(rc);
    }
  }
}

extern "C" void kernel_launch(void* const* d_in, const int* in_sizes, int n_in,
                              void* d_out, int out_size, void* d_ws, size_t ws_size,
                              hipStream_t stream)
{
  const void* state = d_in[0];
  const void* h0    = d_in[1];
  const void* c0    = d_in[2];
  const int*  lens  = (const int*)d_in[3];
  const void* Wih   = d_in[4];
  const void* Whh   = d_in[5];
  const void* bih   = d_in[6];
  const void* bhh   = d_in[7];
  const void* aw0   = d_in[8];
  const void* ab0   = d_in[9];
  const void* aw1   = d_in[10];
  const void* ab1   = d_in[11];
  const void* aw2   = d_in[12];
  const void* ab2   = d_in[13];
  const void* cw0   = d_in[14];
  const void* cb0   = d_in[15];
  const void* cw1   = d_in[16];
  const void* cb1   = d_in[17];
  const void* cw2   = d_in[18];
  const void* cb2   = d_in[19];
  (void)in_sizes; (void)n_in;

  const int N = out_size / 4;             // actor 3N + critic N
  const int Np128 = (N + 127) & ~127;

  char* ws = (char*)d_ws;
  size_t cur = 0;
  auto alloc = [&](size_t bytes)->char*{
    char* p = ws + cur; cur += (bytes + 255) & ~(size_t)255; return p;
  };
  int* mode   = (int*)alloc(4);
  int* off    = (int*)alloc(129*4);
  int* flags  = (int*)alloc(8*T_STEPS*4);
  u16* hbuf   = (u16*)alloc((size_t)2*BATCH*HDIM*2);
  u16* cbf    = (u16*)alloc((size_t)BATCH*HDIM*2);
  u16* wih_b  = (u16*)alloc((size_t)2048*256*2);
  u16* whh_b  = (u16*)alloc((size_t)2048*512*2);
  u16* bih_b  = (u16*)alloc(2048*2);
  u16* bhh_b  = (u16*)alloc(2048*2);
  u16* st_bf  = (u16*)alloc((size_t)T_STEPS*BATCH*DDIM*2);
  u16* wa0    = (u16*)alloc((size_t)512*768*2);
  u16* ba0    = (u16*)alloc(512*2);
  u16* wa1    = (u16*)alloc((size_t)512*512*2);
  u16* ba1    = (u16*)alloc(512*2);
  u16* wa2    = (u16*)alloc(1536*2);
  u16* ba2    = (u16*)alloc(256*2);
  u16* wc0    = (u16*)alloc((size_t)512*768*2);
  u16* bc0    = (u16*)alloc(512*2);
  u16* wc1    = (u16*)alloc((size_t)512*512*2);
  u16* bc1    = (u16*)alloc(512*2);
  u16* wc2    = (u16*)alloc(512*2);
  u16* bc2    = (u16*)alloc(256*2);
  u16* inp    = (u16*)alloc((size_t)Np128*768*2);

  sniff_kernel<<<1, 64, 0, stream>>>((const u16*)bih, mode);

  if (cur > ws_size){
    zero_out_kernel<<<(out_size + 255)/256, 256, 0, stream>>>(d_out, out_size, mode);
    return;
  }
  size_t rem = ws_size - cur;
  long CH_l = (long)((rem / 3) / (512*2)) & ~127L;
  int CH = (int)(CH_l > 8192 ? 8192 : CH_l);
  if (CH < 128){
    zero_out_kernel<<<(out_size + 255)/256, 256, 0, stream>>>(d_out, out_size, mode);
    return;
  }
  u16* bufA = (u16*)alloc((size_t)CH*512*2);
  u16* bufB = (u16*)alloc((size_t)CH*512*2);
  u16* bufC = (u16*)alloc((size_t)CH*512*2);

  auto cvt = [&](const void* src, u16* dst, int n){
    int thr = (n + 7) / 8;
    cvt_kernel<<<(thr + 255)/256, 256, 0, stream>>>(src, dst, n, mode);
  };
  cvt(Wih, wih_b, 2048*256);
  cvt(Whh, whh_b, 2048*512);
  cvt(bih, bih_b, 2048);
  cvt(bhh, bhh_b, 2048);
  cvt(h0,  hbuf + BATCH*HDIM, BATCH*HDIM);   // parity 1 = h_{-1}
  cvt(c0,  cbf, BATCH*HDIM);
  cvt(state, st_bf, T_STEPS*BATCH*DDIM);
  cvt(aw0, wa0, 512*768);  cvt(ab0, ba0, 512);
  cvt(aw1, wa1, 512*512);  cvt(ab1, ba1, 512);
  cvt(aw2, wa2, 1536);     cvt(ab2, ba2, 3);
  cvt(cw0, wc0, 512*768);  cvt(cb0, bc0, 512);
  cvt(cw1, wc1, 512*512);  cvt(cb1, bc1, 512);
  cvt(cw2, wc2, 512);      cvt(cb2, bc2, 1);

  hipMemsetAsync(flags, 0, 8*T_STEPS*4, stream);
  scan_kernel<<<1, 64, 0, stream>>>(lens, off);
  pack_state_kernel<<<(T_STEPS*BATCH)/4, 256, 0, stream>>>(st_bf, lens, off, inp);

  lstm_kernel<<<128, 512, 0, stream>>>(whh_b, wih_b, bih_b, bhh_b, cbf, st_bf,
                                       hbuf, inp, off, lens, flags);

  for (int cs = 0; cs < Np128; cs += CH){
    int rows = (Np128 - cs) < CH ? (Np128 - cs) : CH;
    int gm = rows / 128;
    dim3 gg(gm, 4);
    gemm_kernel<<<gg, 256, 0, stream>>>(inp + (long)cs*768, wa0, ba0, bufA, 768);
    gemm_kernel<<<gg, 256, 0, stream>>>(bufA,               wa1, ba1, bufB, 512);
    gemm_kernel<<<gg, 256, 0, stream>>>(inp + (long)cs*768, wc0, bc0, bufA, 768);
    gemm_kernel<<<gg, 256, 0, stream>>>(bufA,               wc1, bc1, bufC, 512);
    int nvalid = (N - cs) < rows ? (N - cs) : rows;
    if (nvalid > 0)
      final_kernel<<<(nvalid + 3)/4, 256, 0, stream>>>(bufB, bufC, wa2, ba2,
                                                       wc2, bc2, d_out, cs,
                                                       nvalid, N, mode);
  }
}

// Round 6
// 3063.368 us; speedup vs baseline: 4.8914x; 1.9379x over previous
//
#include <hip/hip_runtime.h>
#include <stdint.h>

// RNNPPO: LSTM(512 steps) + ragged pack + 2x MLP heads. DTYPE-ROBUST (sniff
// fp32-vs-bf16, normalize to bf16, output per mode).
//
// R6 (lstm): R5 profiled 10.6us/step with VGPR_Count=72 -> weight fragments
// were NOT register-resident (rematerialized per step), h tile was loaded
// 8x redundantly per WG via uncacheable atomic loads, and 1024 pollers
// hammered 8 flag lines. This round: cooperative LDS h-staging (8x fewer
// atomic loads, -64 live VGPRs so weights fit), two MFMA chains, tid0-only
// poll with s_sleep(2) backoff.

#define T_STEPS 512
#define BATCH   128
#define DDIM    256
#define HDIM    512

typedef __attribute__((ext_vector_type(8))) short bf16x8;
typedef __attribute__((ext_vector_type(4))) float f32x4;
typedef __attribute__((ext_vector_type(2))) unsigned long long u64x2;
typedef unsigned short u16;
typedef unsigned int   u32;
typedef unsigned long long u64;

__device__ __forceinline__ u16 f2bf(float x){
  u32 u = __builtin_bit_cast(u32, x);
  u32 r = u + 0x7fffu + ((u >> 16) & 1u);
  return (u16)(r >> 16);
}
__device__ __forceinline__ float bf2f(u16 h){
  u32 u = ((u32)h) << 16;
  return __builtin_bit_cast(float, u);
}
__device__ __forceinline__ float sigm(float x){ return 1.f/(1.f + __expf(-x)); }
__device__ __forceinline__ float tanh_f(float x){ return 1.f - 2.f/(1.f + __expf(2.f*x)); }

__device__ __forceinline__ void async_ld16(const void* g, void* l){
  __builtin_amdgcn_global_load_lds(
      (const __attribute__((address_space(1))) u32*)g,
      (__attribute__((address_space(3))) u32*)l, 16, 0, 0);
}

// ---------------- dtype sniff ----------------
__global__ void sniff_kernel(const u16* __restrict__ b, int* __restrict__ mode){
  if (threadIdx.x == 0){
    int bad = 0;
    for (int i = 0; i < 64; i++){
      u16 x = b[2*i];
      int e = (x >> 7) & 0xFF;         // bf16 exponent
      if (e < 0x60 || e > 0x85) bad++; // outside ~[2^-31, 2^6]
    }
    *mode = (bad > 16) ? 1 : 0;        // 1 = fp32 inputs, 0 = bf16 inputs
  }
}

// ---------------- convert anything -> bf16 ----------------
__global__ void cvt_kernel(const void* __restrict__ src, u16* __restrict__ dst,
                           int n, const int* __restrict__ mode){
  int i0 = (blockIdx.x*blockDim.x + threadIdx.x) * 8;
  if (i0 >= n) return;
  int m = *mode;
  if (m){
    const float* s = (const float*)src;
    if (i0 + 8 <= n){
      float4 a = *(const float4*)(s + i0);
      float4 b = *(const float4*)(s + i0 + 4);
      ushort4 oa, ob;
      oa.x=f2bf(a.x); oa.y=f2bf(a.y); oa.z=f2bf(a.z); oa.w=f2bf(a.w);
      ob.x=f2bf(b.x); ob.y=f2bf(b.y); ob.z=f2bf(b.z); ob.w=f2bf(b.w);
      *(ushort4*)(dst + i0) = oa;
      *(ushort4*)(dst + i0 + 4) = ob;
    } else {
      for (int i = i0; i < n; i++) dst[i] = f2bf(s[i]);
    }
  } else {
    const u16* s = (const u16*)src;
    if (i0 + 8 <= n){
      *(ushort4*)(dst + i0)     = *(const ushort4*)(s + i0);
      *(ushort4*)(dst + i0 + 4) = *(const ushort4*)(s + i0 + 4);
    } else {
      for (int i = i0; i < n; i++) dst[i] = s[i];
    }
  }
}

// ---------------- prep ----------------
__global__ void scan_kernel(const int* __restrict__ lens, int* __restrict__ off){
  if (threadIdx.x == 0){
    int a = 0;
    for (int b = 0; b < BATCH; b++){ off[b] = a; a += lens[b]; }
    off[BATCH] = a;
  }
}

__global__ void pack_state_kernel(const u16* __restrict__ st_bf,
                                  const int* __restrict__ lens,
                                  const int* __restrict__ off,
                                  u16* __restrict__ inp){
  int r = blockIdx.x*4 + (threadIdx.x >> 6);   // dense row t*BATCH+b
  int lane = threadIdx.x & 63;
  int b = r & (BATCH-1), t = r >> 7;
  if (t >= lens[b]) return;
  long row = (long)off[b] + t;
  ushort4 v = ((const ushort4*)(st_bf + (long)r*DDIM))[lane];
  ((ushort4*)(inp + row*768))[lane] = v;
}

__global__ void zero_out_kernel(void* __restrict__ out, int n,
                                const int* __restrict__ mode){
  int i = blockIdx.x*blockDim.x + threadIdx.x;
  if (i >= n) return;
  if (*mode) ((float*)out)[i] = 0.f; else ((u16*)out)[i] = 0;
}

// ---------------- LSTM recurrence ----------------
__global__ __launch_bounds__(512, 2) void lstm_kernel(
    const u16* __restrict__ Whh, const u16* __restrict__ Wih,
    const u16* __restrict__ bih, const u16* __restrict__ bhh,
    const u16* __restrict__ cell0,
    const u16* __restrict__ state,
    u16* hbuf,                              // [2][BATCH*HDIM]
    u16* __restrict__ inp,                  // [Np128*768]
    const int* __restrict__ off, const int* __restrict__ lens,
    int* flags)                             // [8*T_STEPS]
{
  const int tid  = threadIdx.x;
  const int wave = tid >> 6;
  const int lane = tid & 63;
  const int g    = blockIdx.x >> 4;     // batch group 0..7 (16 batches each)
  const int s    = blockIdx.x & 15;     // col-WG 0..15 (32 h-cols each)
  const int Sb   = s * 32;
  const int gate = wave >> 1;           // 0..3 (i,f,g,o)
  const int hf   = wave & 1;            // column half
  const int q    = lane >> 4;
  const int m16  = lane & 15;
  const int colg = gate*HDIM + Sb + hf*16 + m16;   // global gate column

  // h tile of this group staged in frag order: chunk m = c*64 + l holds
  // h[row=l&15][k = c*32 + (l>>4)*8 .. +8] (16 B). ds_read_b128 by (c,lane)
  // is then contiguous across lanes -> max LDS rate, no conflicts.
  __shared__ u16  hlds[8192];           // 16 KB
  __shared__ float lds_acc[8][16][16];
  __shared__ float bias_l[128];
  __shared__ int   len_l[16];
  __shared__ int   off_l[16];

  if (tid < 128){
    int gt = tid >> 5, jx = tid & 31;
    int cg = gt*HDIM + Sb + jx;
    bias_l[tid] = bf2f(bih[cg]) + bf2f(bhh[cg]);
  }
  if (tid < 16){ len_l[tid] = lens[g*16 + tid]; off_l[tid] = off[g*16 + tid]; }

  // weight fragments (B operand: lane holds W[col][k], k=c*32+q*8+j) —
  // with h staged through LDS the live-VGPR budget now fits these resident.
  bf16x8 whh[16], wih[8];
  {
    const u16* wb = Whh + (long)colg*HDIM + q*8;
    #pragma unroll
    for (int c = 0; c < 16; c++) whh[c] = *(const bf16x8*)(wb + c*32);
    const u16* wb2 = Wih + (long)colg*DDIM + q*8;
    #pragma unroll
    for (int c = 0; c < 8; c++) wih[c] = *(const bf16x8*)(wb2 + c*32);
  }

  const int b_l = tid >> 5;    // epilogue ownership: (batch b_l, col j)
  const int j   = tid & 31;
  const int hx  = j >> 4;
  const int jj  = j & 15;
  float cval = bf2f(cell0[(g*16 + b_l)*HDIM + Sb + j]);

  __syncthreads();

  const int fbase = g * T_STEPS;

  for (int t = 0; t < T_STEPS; t++){
    f32x4 acc  = {0.f, 0.f, 0.f, 0.f};
    f32x4 acc2 = {0.f, 0.f, 0.f, 0.f};
    // x-part: independent of h, issued before the spin (sync-shadow prefetch)
    {
      const u16* xb = state + ((long)(t*BATCH + g*16 + m16))*DDIM + q*8;
      #pragma unroll
      for (int c = 0; c < 8; c++){
        bf16x8 a = *(const bf16x8*)(xb + c*32);
        acc = __builtin_amdgcn_mfma_f32_16x16x32_bf16(a, wih[c], acc, 0, 0, 0);
      }
    }
    // single poller per WG (tid0), backoff sleep; bounded so a wedge is a
    // wrong answer, not a hang.
    if (t > 0){
      if (tid == 0){
        int spins = 0;
        while (__hip_atomic_load(&flags[fbase + t - 1], __ATOMIC_RELAXED,
                                 __HIP_MEMORY_SCOPE_AGENT) < 16){
          if (++spins > (1 << 16)) break;
          __builtin_amdgcn_s_sleep(2);
        }
      }
      __syncthreads();
      asm volatile("" ::: "memory");
    }
    // cooperative h stage: 512 threads x (4 atomic u64 loads + 16B LDS
    // writes) cover the 16 KB tile once (was 8x redundant per-wave loads)
    {
      const u16* hp = hbuf + ((t & 1) ^ 1)*(BATCH*HDIM) + (size_t)g*16*HDIM;
      #pragma unroll
      for (int p = 0; p < 2; p++){
        int m = tid*2 + p;
        int c = m >> 6, l = m & 63;
        int row = l & 15;
        int k = c*32 + (l >> 4)*8;
        const u64* src = (const u64*)(hp + row*HDIM + k);
        u64 a0 = __hip_atomic_load(src,     __ATOMIC_RELAXED,
                                   __HIP_MEMORY_SCOPE_AGENT);
        u64 a1 = __hip_atomic_load(src + 1, __ATOMIC_RELAXED,
                                   __HIP_MEMORY_SCOPE_AGENT);
        u64x2 v; v[0] = a0; v[1] = a1;
        *(u64x2*)(&hlds[m*8]) = v;
      }
    }
    __syncthreads();
    // h-part: fragments from LDS, two interleaved MFMA chains
    #pragma unroll
    for (int cc = 0; cc < 8; cc++){
      bf16x8 a0 = *(const bf16x8*)(&hlds[((2*cc    )*64 + lane)*8]);
      bf16x8 a1 = *(const bf16x8*)(&hlds[((2*cc + 1)*64 + lane)*8]);
      acc  = __builtin_amdgcn_mfma_f32_16x16x32_bf16(a0, whh[2*cc    ], acc,  0, 0, 0);
      acc2 = __builtin_amdgcn_mfma_f32_16x16x32_bf16(a1, whh[2*cc + 1], acc2, 0, 0, 0);
    }
    // gate exchange through LDS (C layout: row(batch)=q*4+r, col=lane&15)
    #pragma unroll
    for (int r = 0; r < 4; r++)
      lds_acc[wave][q*4 + r][m16] = acc[r] + acc2[r];
    __syncthreads();

    float iv = lds_acc[0 + hx][b_l][jj] + bias_l[ 0 + j];
    float fv = lds_acc[2 + hx][b_l][jj] + bias_l[32 + j];
    float gv = lds_acc[4 + hx][b_l][jj] + bias_l[64 + j];
    float ov = lds_acc[6 + hx][b_l][jj] + bias_l[96 + j];
    cval = sigm(fv)*cval + sigm(iv)*tanh_f(gv);
    float hv = sigm(ov)*tanh_f(cval);
    u16 hb16 = f2bf(hv);
    // pair adjacent columns (j, j+1): one u32 relaxed agent store (LLC
    // write-through; no dirty L2 lines -> no cache maintenance ever)
    int nb = __shfl_down((int)hb16, 1);
    if ((j & 1) == 0){
      size_t hidx = (size_t)(t & 1)*(BATCH*HDIM) + (g*16 + b_l)*HDIM + Sb + j;
      u32 pair = (u32)hb16 | ((u32)(u16)nb << 16);
      __hip_atomic_store((u32*)(hbuf + hidx), pair,
                         __ATOMIC_RELAXED, __HIP_MEMORY_SCOPE_AGENT);
    }
    __builtin_amdgcn_s_waitcnt(0);   // own store ack'd at LLC
    __syncthreads();                 // all threads' stores ack'd
    if (tid == 0)
      __hip_atomic_fetch_add(&flags[fbase + t], 1, __ATOMIC_RELAXED,
                             __HIP_MEMORY_SCOPE_AGENT);
    // packed-h store is off the critical path (consumed only after kernel end)
    if (t < len_l[b_l])
      inp[((long)(off_l[b_l] + t))*768 + DDIM + Sb + j] = hb16;
  }
}

// ---------------- MLP GEMM: C = relu(A @ W^T + bias), bf16 in/out ----------------
__global__ __launch_bounds__(256) void gemm_kernel(
    const u16* __restrict__ A,   // [rows x K]
    const u16* __restrict__ W,   // [512 x K]
    const u16* __restrict__ bias,
    u16* __restrict__ C,         // [rows x 512]
    int K)
{
  __shared__ u16 As[128*32];
  __shared__ u16 Bs[128*32];
  const int tid = threadIdx.x, wave = tid >> 6, lane = tid & 63;
  const int bm = blockIdx.x * 128;
  const int bn = blockIdx.y * 128;
  const int wr = (wave >> 1) * 64;
  const int wc = (wave & 1) * 64;
  const int q = lane >> 4, m16 = lane & 15;
  const int rsub = lane >> 2;          // 0..15
  const int ksub = (lane & 3) * 8;     // elems

  f32x4 acc[4][4] = {};

  for (int k0 = 0; k0 < K; k0 += 32){
    __syncthreads();
    #pragma unroll
    for (int i = 0; i < 2; i++){
      int rr = (i*4 + wave) * 16 + rsub;
      async_ld16(A + (long)(bm + rr)*K + k0 + ksub, As + (i*4 + wave)*512);
      async_ld16(W + (long)(bn + rr)*K + k0 + ksub, Bs + (i*4 + wave)*512);
    }
    __syncthreads();
    bf16x8 af[4], bfr[4];
    #pragma unroll
    for (int r = 0; r < 4; r++) af[r]  = *(const bf16x8*)(As + (wr + r*16 + m16)*32 + q*8);
    #pragma unroll
    for (int c = 0; c < 4; c++) bfr[c] = *(const bf16x8*)(Bs + (wc + c*16 + m16)*32 + q*8);
    #pragma unroll
    for (int r = 0; r < 4; r++)
      #pragma unroll
      for (int c = 0; c < 4; c++)
        acc[r][c] = __builtin_amdgcn_mfma_f32_16x16x32_bf16(af[r], bfr[c], acc[r][c], 0, 0, 0);
  }
  #pragma unroll
  for (int c = 0; c < 4; c++){
    int col = bn + wc + c*16 + m16;
    float bv = bf2f(bias[col]);
    #pragma unroll
    for (int r = 0; r < 4; r++){
      #pragma unroll
      for (int x = 0; x < 4; x++){
        int row = bm + wr + r*16 + q*4 + x;
        float v = acc[r][c][x] + bv;
        v = fmaxf(v, 0.f);
        C[(long)row*512 + col] = f2bf(v);
      }
    }
  }
}

// ---------------- final fused layer: actor(3, tanh) + critic(1) ----------------
__global__ void final_kernel(
    const u16* __restrict__ a2, const u16* __restrict__ c2,
    const u16* __restrict__ aw2, const u16* __restrict__ ab2,
    const u16* __restrict__ cw2, const u16* __restrict__ cb2,
    void* __restrict__ out, int base, int nvalid, int N,
    const int* __restrict__ mode)
{
  int lw = (blockIdx.x * blockDim.x + threadIdx.x) >> 6;   // local row
  int lane = threadIdx.x & 63;
  if (lw >= nvalid) return;
  int k = lane * 8;
  bf16x8 av = *(const bf16x8*)(a2 + (long)lw*512 + k);
  bf16x8 cv = *(const bf16x8*)(c2 + (long)lw*512 + k);
  bf16x8 w0 = *(const bf16x8*)(aw2 + k);
  bf16x8 w1 = *(const bf16x8*)(aw2 + 512 + k);
  bf16x8 w2 = *(const bf16x8*)(aw2 + 1024 + k);
  bf16x8 wc = *(const bf16x8*)(cw2 + k);
  float d0=0.f, d1=0.f, d2=0.f, dc=0.f;
  #pragma unroll
  for (int x = 0; x < 8; x++){
    float a  = bf2f((u16)av[x]);
    float cc = bf2f((u16)cv[x]);
    d0 += a  * bf2f((u16)w0[x]);
    d1 += a  * bf2f((u16)w1[x]);
    d2 += a  * bf2f((u16)w2[x]);
    dc += cc * bf2f((u16)wc[x]);
  }
  #pragma unroll
  for (int o = 32; o > 0; o >>= 1){
    d0 += __shfl_down(d0, o);
    d1 += __shfl_down(d1, o);
    d2 += __shfl_down(d2, o);
    dc += __shfl_down(dc, o);
  }
  if (lane == 0){
    int gr = base + lw;
    float r0 = tanh_f(d0 + bf2f(ab2[0]));
    float r1 = tanh_f(d1 + bf2f(ab2[1]));
    float r2 = tanh_f(d2 + bf2f(ab2[2]));
    float rc = dc + bf2f(cb2[0]);
    if (*mode){
      float* o = (float*)out;
      o[(long)gr*3 + 0] = r0; o[(long)gr*3 + 1] = r1; o[(long)gr*3 + 2] = r2;
      o[(long)3*N + gr] = rc;
    } else {
      u16* o = (u16*)out;
      o[(long)gr*3 + 0] = f2bf(r0); o[(long)gr*3 + 1] = f2bf(r1);
      o[(long)gr*3 + 2] = f2bf(r2);
      o[(long)3*N + gr] = f2bf(rc);
    }
  }
}

extern "C" void kernel_launch(void* const* d_in, const int* in_sizes, int n_in,
                              void* d_out, int out_size, void* d_ws, size_t ws_size,
                              hipStream_t stream)
{
  const void* state = d_in[0];
  const void* h0    = d_in[1];
  const void* c0    = d_in[2];
  const int*  lens  = (const int*)d_in[3];
  const void* Wih   = d_in[4];
  const void* Whh   = d_in[5];
  const void* bih   = d_in[6];
  const void* bhh   = d_in[7];
  const void* aw0   = d_in[8];
  const void* ab0   = d_in[9];
  const void* aw1   = d_in[10];
  const void* ab1   = d_in[11];
  const void* aw2   = d_in[12];
  const void* ab2   = d_in[13];
  const void* cw0   = d_in[14];
  const void* cb0   = d_in[15];
  const void* cw1   = d_in[16];
  const void* cb1   = d_in[17];
  const void* cw2   = d_in[18];
  const void* cb2   = d_in[19];
  (void)in_sizes; (void)n_in;

  const int N = out_size / 4;             // actor 3N + critic N
  const int Np128 = (N + 127) & ~127;

  char* ws = (char*)d_ws;
  size_t cur = 0;
  auto alloc = [&](size_t bytes)->char*{
    char* p = ws + cur; cur += (bytes + 255) & ~(size_t)255; return p;
  };
  int* mode   = (int*)alloc(4);
  int* off    = (int*)alloc(129*4);
  int* flags  = (int*)alloc(8*T_STEPS*4);
  u16* hbuf   = (u16*)alloc((size_t)2*BATCH*HDIM*2);
  u16* cbf    = (u16*)alloc((size_t)BATCH*HDIM*2);
  u16* wih_b  = (u16*)alloc((size_t)2048*256*2);
  u16* whh_b  = (u16*)alloc((size_t)2048*512*2);
  u16* bih_b  = (u16*)alloc(2048*2);
  u16* bhh_b  = (u16*)alloc(2048*2);
  u16* st_bf  = (u16*)alloc((size_t)T_STEPS*BATCH*DDIM*2);
  u16* wa0    = (u16*)alloc((size_t)512*768*2);
  u16* ba0    = (u16*)alloc(512*2);
  u16* wa1    = (u16*)alloc((size_t)512*512*2);
  u16* ba1    = (u16*)alloc(512*2);
  u16* wa2    = (u16*)alloc(1536*2);
  u16* ba2    = (u16*)alloc(256*2);
  u16* wc0    = (u16*)alloc((size_t)512*768*2);
  u16* bc0    = (u16*)alloc(512*2);
  u16* wc1    = (u16*)alloc((size_t)512*512*2);
  u16* bc1    = (u16*)alloc(512*2);
  u16* wc2    = (u16*)alloc(512*2);
  u16* bc2    = (u16*)alloc(256*2);
  u16* inp    = (u16*)alloc((size_t)Np128*768*2);

  sniff_kernel<<<1, 64, 0, stream>>>((const u16*)bih, mode);

  if (cur > ws_size){
    zero_out_kernel<<<(out_size + 255)/256, 256, 0, stream>>>(d_out, out_size, mode);
    return;
  }
  size_t rem = ws_size - cur;
  long CH_l = (long)((rem / 3) / (512*2)) & ~127L;
  int CH = (int)(CH_l > 8192 ? 8192 : CH_l);
  if (CH < 128){
    zero_out_kernel<<<(out_size + 255)/256, 256, 0, stream>>>(d_out, out_size, mode);
    return;
  }
  u16* bufA = (u16*)alloc((size_t)CH*512*2);
  u16* bufB = (u16*)alloc((size_t)CH*512*2);
  u16* bufC = (u16*)alloc((size_t)CH*512*2);

  auto cvt = [&](const void* src, u16* dst, int n){
    int thr = (n + 7) / 8;
    cvt_kernel<<<(thr + 255)/256, 256, 0, stream>>>(src, dst, n, mode);
  };
  cvt(Wih, wih_b, 2048*256);
  cvt(Whh, whh_b, 2048*512);
  cvt(bih, bih_b, 2048);
  cvt(bhh, bhh_b, 2048);
  cvt(h0,  hbuf + BATCH*HDIM, BATCH*HDIM);   // parity 1 = h_{-1}
  cvt(c0,  cbf, BATCH*HDIM);
  cvt(state, st_bf, T_STEPS*BATCH*DDIM);
  cvt(aw0, wa0, 512*768);  cvt(ab0, ba0, 512);
  cvt(aw1, wa1, 512*512);  cvt(ab1, ba1, 512);
  cvt(aw2, wa2, 1536);     cvt(ab2, ba2, 3);
  cvt(cw0, wc0, 512*768);  cvt(cb0, bc0, 512);
  cvt(cw1, wc1, 512*512);  cvt(cb1, bc1, 512);
  cvt(cw2, wc2, 512);      cvt(cb2, bc2, 1);

  hipMemsetAsync(flags, 0, 8*T_STEPS*4, stream);
  scan_kernel<<<1, 64, 0, stream>>>(lens, off);
  pack_state_kernel<<<(T_STEPS*BATCH)/4, 256, 0, stream>>>(st_bf, lens, off, inp);

  lstm_kernel<<<128, 512, 0, stream>>>(whh_b, wih_b, bih_b, bhh_b, cbf, st_bf,
                                       hbuf, inp, off, lens, flags);

  for (int cs = 0; cs < Np128; cs += CH){
    int rows = (Np128 - cs) < CH ? (Np128 - cs) : CH;
    int gm = rows / 128;
    dim3 gg(gm, 4);
    gemm_kernel<<<gg, 256, 0, stream>>>(inp + (long)cs*768, wa0, ba0, bufA, 768);
    gemm_kernel<<<gg, 256, 0, stream>>>(bufA,               wa1, ba1, bufB, 512);
    gemm_kernel<<<gg, 256, 0, stream>>>(inp + (long)cs*768, wc0, bc0, bufA, 768);
    gemm_kernel<<<gg, 256, 0, stream>>>(bufA,               wc1, bc1, bufC, 512);
    int nvalid = (N - cs) < rows ? (N - cs) : rows;
    if (nvalid > 0)
      final_kernel<<<(nvalid + 3)/4, 256, 0, stream>>>(bufB, bufC, wa2, ba2,
                                                       wc2, bc2, d_out, cs,
                                                       nvalid, N, mode);
  }
}

// Round 7
// 3011.010 us; speedup vs baseline: 4.9765x; 1.0174x over previous
//
#include <hip/hip_runtime.h>
#include <stdint.h>

// RNNPPO: LSTM(512 steps) + ragged pack + 2x MLP heads. DTYPE-ROBUST (sniff
// fp32-vs-bf16, normalize to bf16, output per mode).
//
// R7 (lstm): R6 still showed VGPR=72 (weights rematerialized every step) and
// a 4-5 LLC-round-trip sync chain (store ack -> WG barrier -> 16-way RMW on
// one flag line -> sleep-quantized poll -> co-op load). This round:
//  - Whh slice LDS-resident (128 KB/WG; 156 KB total LDS, 1 WG/CU) -> zero
//    per-step weight traffic, no remat gamble.
//  - per-(WG,batch) tag release: wave-level s_waitcnt + tag store (no
//    producer barrier, no RMW contention, no s_sleep); consumers poll their
//    own segment tag and load early segments while late producers finish.
//  - 2 barriers/step (was 4); x-MFMAs execute in the h-load shadow.

#define T_STEPS 512
#define BATCH   128
#define DDIM    256
#define HDIM    512

typedef __attribute__((ext_vector_type(8))) short bf16x8;
typedef __attribute__((ext_vector_type(4))) float f32x4;
typedef __attribute__((ext_vector_type(2))) unsigned long long u64x2;
typedef unsigned short u16;
typedef unsigned int   u32;
typedef unsigned long long u64;

__device__ __forceinline__ u16 f2bf(float x){
  u32 u = __builtin_bit_cast(u32, x);
  u32 r = u + 0x7fffu + ((u >> 16) & 1u);
  return (u16)(r >> 16);
}
__device__ __forceinline__ float bf2f(u16 h){
  u32 u = ((u32)h) << 16;
  return __builtin_bit_cast(float, u);
}
__device__ __forceinline__ float sigm(float x){ return 1.f/(1.f + __expf(-x)); }
__device__ __forceinline__ float tanh_f(float x){ return 1.f - 2.f/(1.f + __expf(2.f*x)); }

__device__ __forceinline__ void async_ld16(const void* g, void* l){
  __builtin_amdgcn_global_load_lds(
      (const __attribute__((address_space(1))) u32*)g,
      (__attribute__((address_space(3))) u32*)l, 16, 0, 0);
}

// ---------------- dtype sniff ----------------
__global__ void sniff_kernel(const u16* __restrict__ b, int* __restrict__ mode){
  if (threadIdx.x == 0){
    int bad = 0;
    for (int i = 0; i < 64; i++){
      u16 x = b[2*i];
      int e = (x >> 7) & 0xFF;         // bf16 exponent
      if (e < 0x60 || e > 0x85) bad++; // outside ~[2^-31, 2^6]
    }
    *mode = (bad > 16) ? 1 : 0;        // 1 = fp32 inputs, 0 = bf16 inputs
  }
}

// ---------------- convert anything -> bf16 ----------------
__global__ void cvt_kernel(const void* __restrict__ src, u16* __restrict__ dst,
                           int n, const int* __restrict__ mode){
  int i0 = (blockIdx.x*blockDim.x + threadIdx.x) * 8;
  if (i0 >= n) return;
  int m = *mode;
  if (m){
    const float* s = (const float*)src;
    if (i0 + 8 <= n){
      float4 a = *(const float4*)(s + i0);
      float4 b = *(const float4*)(s + i0 + 4);
      ushort4 oa, ob;
      oa.x=f2bf(a.x); oa.y=f2bf(a.y); oa.z=f2bf(a.z); oa.w=f2bf(a.w);
      ob.x=f2bf(b.x); ob.y=f2bf(b.y); ob.z=f2bf(b.z); ob.w=f2bf(b.w);
      *(ushort4*)(dst + i0) = oa;
      *(ushort4*)(dst + i0 + 4) = ob;
    } else {
      for (int i = i0; i < n; i++) dst[i] = f2bf(s[i]);
    }
  } else {
    const u16* s = (const u16*)src;
    if (i0 + 8 <= n){
      *(ushort4*)(dst + i0)     = *(const ushort4*)(s + i0);
      *(ushort4*)(dst + i0 + 4) = *(const ushort4*)(s + i0 + 4);
    } else {
      for (int i = i0; i < n; i++) dst[i] = s[i];
    }
  }
}

// ---------------- prep ----------------
__global__ void scan_kernel(const int* __restrict__ lens, int* __restrict__ off){
  if (threadIdx.x == 0){
    int a = 0;
    for (int b = 0; b < BATCH; b++){ off[b] = a; a += lens[b]; }
    off[BATCH] = a;
  }
}

__global__ void pack_state_kernel(const u16* __restrict__ st_bf,
                                  const int* __restrict__ lens,
                                  const int* __restrict__ off,
                                  u16* __restrict__ inp){
  int r = blockIdx.x*4 + (threadIdx.x >> 6);   // dense row t*BATCH+b
  int lane = threadIdx.x & 63;
  int b = r & (BATCH-1), t = r >> 7;
  if (t >= lens[b]) return;
  long row = (long)off[b] + t;
  ushort4 v = ((const ushort4*)(st_bf + (long)r*DDIM))[lane];
  ((ushort4*)(inp + row*768))[lane] = v;
}

__global__ void zero_out_kernel(void* __restrict__ out, int n,
                                const int* __restrict__ mode){
  int i = blockIdx.x*blockDim.x + threadIdx.x;
  if (i >= n) return;
  if (*mode) ((float*)out)[i] = 0.f; else ((u16*)out)[i] = 0;
}

// ---------------- LSTM recurrence ----------------
__global__ __launch_bounds__(512, 1) void lstm_kernel(
    const u16* __restrict__ Whh, const u16* __restrict__ Wih,
    const u16* __restrict__ bih, const u16* __restrict__ bhh,
    const u16* __restrict__ cell0,
    const u16* __restrict__ state,
    u16* hbuf,                              // [2][BATCH*HDIM]
    u16* __restrict__ inp,                  // [Np128*768]
    const int* __restrict__ off, const int* __restrict__ lens,
    int* tags)                              // [8*256] per-(g,s,b) step tags
{
  const int tid  = threadIdx.x;
  const int wave = tid >> 6;
  const int lane = tid & 63;
  const int g    = blockIdx.x >> 4;     // batch group 0..7 (16 batches each)
  const int s    = blockIdx.x & 15;     // col-WG 0..15 (32 h-cols each)
  const int Sb   = s * 32;
  const int q    = lane >> 4;
  const int m16  = lane & 15;

  // LDS: Whh slice (128 gate-cols x 512 K) in frag order + h tile + acc xchg
  __shared__ u16  wlds[65536];          // 128 KB
  __shared__ u16  hlds[8192];           // 16 KB
  __shared__ float lds_acc[8][16][16];  // 8 KB
  __shared__ float bias_l[128];
  __shared__ int   len_l[16];
  __shared__ int   off_l[16];

  if (tid < 128){
    int gt = tid >> 5, jx = tid & 31;
    int cg = gt*HDIM + Sb + jx;
    bias_l[tid] = bf2f(bih[cg]) + bf2f(bhh[cg]);
  }
  if (tid < 16){ len_l[tid] = lens[g*16 + tid]; off_l[tid] = off[g*16 + tid]; }

  // one-time: stage Whh slice into LDS, frag order:
  // chunk ch = (w*16 + c)*64 + l  holds  W[col(w, l&15)][c*32 + (l>>4)*8 ..+8]
  for (int i = 0; i < 16; i++){
    int ch = tid + 512*i;               // 0..8191
    int w = ch >> 10;
    int rem = ch & 1023;
    int c = rem >> 6;
    int l = rem & 63;
    int col = (w >> 1)*HDIM + Sb + (w & 1)*16 + (l & 15);
    int k = c*32 + (l >> 4)*8;
    u64x2 v = *(const u64x2*)(Whh + (long)col*HDIM + k);
    *(u64x2*)(&wlds[(size_t)ch*8]) = v;
  }

  // Wih fragments in VGPRs (32 VGPRs; even if rematerialized, the reloads
  // sit in the x-stage which is off the sync critical path)
  const int gate = wave >> 1;
  const int hf   = wave & 1;
  const int colg = gate*HDIM + Sb + hf*16 + m16;
  bf16x8 wih[8];
  {
    const u16* wb2 = Wih + (long)colg*DDIM + q*8;
    #pragma unroll
    for (int c = 0; c < 8; c++) wih[c] = *(const bf16x8*)(wb2 + c*32);
  }

  const int b_l = tid >> 5;    // epilogue ownership: (batch b_l, col j)
  const int j   = tid & 31;
  const int hx  = j >> 4;
  const int jj  = j & 15;
  float cval = bf2f(cell0[(g*16 + b_l)*HDIM + Sb + j]);

  // consumer co-op chunk assignment (2 chunks/thread, conflict-free writes)
  const int m0 = tid, m1 = tid + 512;
  const int c0i = m0 >> 6, c1i = m1 >> 6;
  const int r0 = m0 & 15;                 // == m1 & 15
  const int k0 = c0i*32 + ((m0 & 63) >> 4)*8;
  const int k1 = c1i*32 + ((m1 & 63) >> 4)*8;

  __syncthreads();

  for (int t = 0; t < T_STEPS; t++){
    f32x4 acc  = {0.f, 0.f, 0.f, 0.f};
    f32x4 acc2 = {0.f, 0.f, 0.f, 0.f};
    // A: x loads issue (normal cached; land during poll/h-load shadow)
    bf16x8 xa[8];
    {
      const u16* xb = state + ((long)(t*BATCH + g*16 + m16))*DDIM + q*8;
      #pragma unroll
      for (int c = 0; c < 8; c++) xa[c] = *(const bf16x8*)(xb + c*32);
    }
    // B: per-segment tag poll (relaxed agent atomics = coherent LLC loads),
    // then h atomic loads. Bounded spin: wedge -> wrong answer, not a hang.
    const u16* hp = hbuf + ((t & 1) ^ 1)*(BATCH*HDIM) + (size_t)g*16*HDIM;
    if (t > 0){
      int* tg = tags + g*256;
      int spins = 0;
      while (__hip_atomic_load(&tg[c0i*16 + r0], __ATOMIC_RELAXED,
                               __HIP_MEMORY_SCOPE_AGENT) < t){
        if (++spins > (1 << 16)) break;
      }
      spins = 0;
      while (__hip_atomic_load(&tg[c1i*16 + r0], __ATOMIC_RELAXED,
                               __HIP_MEMORY_SCOPE_AGENT) < t){
        if (++spins > (1 << 16)) break;
      }
      asm volatile("" ::: "memory");   // no hoisting h loads above polls
    }
    const u64* s0p = (const u64*)(hp + r0*HDIM + k0);
    const u64* s1p = (const u64*)(hp + r0*HDIM + k1);
    u64 a00 = __hip_atomic_load(s0p,     __ATOMIC_RELAXED, __HIP_MEMORY_SCOPE_AGENT);
    u64 a01 = __hip_atomic_load(s0p + 1, __ATOMIC_RELAXED, __HIP_MEMORY_SCOPE_AGENT);
    u64 a10 = __hip_atomic_load(s1p,     __ATOMIC_RELAXED, __HIP_MEMORY_SCOPE_AGENT);
    u64 a11 = __hip_atomic_load(s1p + 1, __ATOMIC_RELAXED, __HIP_MEMORY_SCOPE_AGENT);
    // C: x MFMAs execute while h loads are in flight
    #pragma unroll
    for (int c = 0; c < 8; c++)
      acc = __builtin_amdgcn_mfma_f32_16x16x32_bf16(xa[c], wih[c], acc, 0, 0, 0);
    // D: h tile -> LDS (consecutive 16B per thread, conflict-free)
    { u64x2 v; v[0] = a00; v[1] = a01; *(u64x2*)(&hlds[(size_t)m0*8]) = v; }
    { u64x2 v; v[0] = a10; v[1] = a11; *(u64x2*)(&hlds[(size_t)m1*8]) = v; }
    __syncthreads();                   // barrier 1: hlds ready
    // E: h MFMAs, weights from LDS (two interleaved chains)
    #pragma unroll
    for (int cc = 0; cc < 8; cc++){
      bf16x8 a0 = *(const bf16x8*)(&hlds[(size_t)((2*cc    )*64 + lane)*8]);
      bf16x8 a1 = *(const bf16x8*)(&hlds[(size_t)((2*cc + 1)*64 + lane)*8]);
      bf16x8 w0 = *(const bf16x8*)(&wlds[(size_t)((wave*16 + 2*cc    )*64 + lane)*8]);
      bf16x8 w1 = *(const bf16x8*)(&wlds[(size_t)((wave*16 + 2*cc + 1)*64 + lane)*8]);
      acc  = __builtin_amdgcn_mfma_f32_16x16x32_bf16(a0, w0, acc,  0, 0, 0);
      acc2 = __builtin_amdgcn_mfma_f32_16x16x32_bf16(a1, w1, acc2, 0, 0, 0);
    }
    // F: gate exchange through LDS (C layout: row(batch)=q*4+r, col=m16)
    #pragma unroll
    for (int r = 0; r < 4; r++)
      lds_acc[wave][q*4 + r][m16] = acc[r] + acc2[r];
    __syncthreads();                   // barrier 2: gates ready

    // G: epilogue + wave-level release (no end-of-step barrier needed)
    float iv = lds_acc[0 + hx][b_l][jj] + bias_l[ 0 + j];
    float fv = lds_acc[2 + hx][b_l][jj] + bias_l[32 + j];
    float gv = lds_acc[4 + hx][b_l][jj] + bias_l[64 + j];
    float ov = lds_acc[6 + hx][b_l][jj] + bias_l[96 + j];
    cval = sigm(fv)*cval + sigm(iv)*tanh_f(gv);
    float hv = sigm(ov)*tanh_f(cval);
    u16 hb16 = f2bf(hv);
    int nb = __shfl_down((int)hb16, 1);
    if ((j & 1) == 0){
      size_t hidx = (size_t)(t & 1)*(BATCH*HDIM) + (g*16 + b_l)*HDIM + Sb + j;
      u32 pair = (u32)hb16 | ((u32)(u16)nb << 16);
      __hip_atomic_store((u32*)(hbuf + hidx), pair,
                         __ATOMIC_RELAXED, __HIP_MEMORY_SCOPE_AGENT);
    }
    __builtin_amdgcn_s_waitcnt(0);     // own wave's h stores ack'd at LLC
    if ((tid & 31) == 0)
      __hip_atomic_store(&tags[g*256 + s*16 + b_l], t + 1,
                         __ATOMIC_RELAXED, __HIP_MEMORY_SCOPE_AGENT);
    // packed-h store off the release path
    if (t < len_l[b_l])
      inp[((long)(off_l[b_l] + t))*768 + DDIM + Sb + j] = hb16;
  }
}

// ---------------- MLP GEMM: C = relu(A @ W^T + bias), bf16 in/out ----------------
__global__ __launch_bounds__(256) void gemm_kernel(
    const u16* __restrict__ A,   // [rows x K]
    const u16* __restrict__ W,   // [512 x K]
    const u16* __restrict__ bias,
    u16* __restrict__ C,         // [rows x 512]
    int K)
{
  __shared__ u16 As[128*32];
  __shared__ u16 Bs[128*32];
  const int tid = threadIdx.x, wave = tid >> 6, lane = tid & 63;
  const int bm = blockIdx.x * 128;
  const int bn = blockIdx.y * 128;
  const int wr = (wave >> 1) * 64;
  const int wc = (wave & 1) * 64;
  const int q = lane >> 4, m16 = lane & 15;
  const int rsub = lane >> 2;          // 0..15
  const int ksub = (lane & 3) * 8;     // elems

  f32x4 acc[4][4] = {};

  for (int k0 = 0; k0 < K; k0 += 32){
    __syncthreads();
    #pragma unroll
    for (int i = 0; i < 2; i++){
      int rr = (i*4 + wave) * 16 + rsub;
      async_ld16(A + (long)(bm + rr)*K + k0 + ksub, As + (i*4 + wave)*512);
      async_ld16(W + (long)(bn + rr)*K + k0 + ksub, Bs + (i*4 + wave)*512);
    }
    __syncthreads();
    bf16x8 af[4], bfr[4];
    #pragma unroll
    for (int r = 0; r < 4; r++) af[r]  = *(const bf16x8*)(As + (wr + r*16 + m16)*32 + q*8);
    #pragma unroll
    for (int c = 0; c < 4; c++) bfr[c] = *(const bf16x8*)(Bs + (wc + c*16 + m16)*32 + q*8);
    #pragma unroll
    for (int r = 0; r < 4; r++)
      #pragma unroll
      for (int c = 0; c < 4; c++)
        acc[r][c] = __builtin_amdgcn_mfma_f32_16x16x32_bf16(af[r], bfr[c], acc[r][c], 0, 0, 0);
  }
  #pragma unroll
  for (int c = 0; c < 4; c++){
    int col = bn + wc + c*16 + m16;
    float bv = bf2f(bias[col]);
    #pragma unroll
    for (int r = 0; r < 4; r++){
      #pragma unroll
      for (int x = 0; x < 4; x++){
        int row = bm + wr + r*16 + q*4 + x;
        float v = acc[r][c][x] + bv;
        v = fmaxf(v, 0.f);
        C[(long)row*512 + col] = f2bf(v);
      }
    }
  }
}

// ---------------- final fused layer: actor(3, tanh) + critic(1) ----------------
__global__ void final_kernel(
    const u16* __restrict__ a2, const u16* __restrict__ c2,
    const u16* __restrict__ aw2, const u16* __restrict__ ab2,
    const u16* __restrict__ cw2, const u16* __restrict__ cb2,
    void* __restrict__ out, int base, int nvalid, int N,
    const int* __restrict__ mode)
{
  int lw = (blockIdx.x * blockDim.x + threadIdx.x) >> 6;   // local row
  int lane = threadIdx.x & 63;
  if (lw >= nvalid) return;
  int k = lane * 8;
  bf16x8 av = *(const bf16x8*)(a2 + (long)lw*512 + k);
  bf16x8 cv = *(const bf16x8*)(c2 + (long)lw*512 + k);
  bf16x8 w0 = *(const bf16x8*)(aw2 + k);
  bf16x8 w1 = *(const bf16x8*)(aw2 + 512 + k);
  bf16x8 w2 = *(const bf16x8*)(aw2 + 1024 + k);
  bf16x8 wc = *(const bf16x8*)(cw2 + k);
  float d0=0.f, d1=0.f, d2=0.f, dc=0.f;
  #pragma unroll
  for (int x = 0; x < 8; x++){
    float a  = bf2f((u16)av[x]);
    float cc = bf2f((u16)cv[x]);
    d0 += a  * bf2f((u16)w0[x]);
    d1 += a  * bf2f((u16)w1[x]);
    d2 += a  * bf2f((u16)w2[x]);
    dc += cc * bf2f((u16)wc[x]);
  }
  #pragma unroll
  for (int o = 32; o > 0; o >>= 1){
    d0 += __shfl_down(d0, o);
    d1 += __shfl_down(d1, o);
    d2 += __shfl_down(d2, o);
    dc += __shfl_down(dc, o);
  }
  if (lane == 0){
    int gr = base + lw;
    float r0 = tanh_f(d0 + bf2f(ab2[0]));
    float r1 = tanh_f(d1 + bf2f(ab2[1]));
    float r2 = tanh_f(d2 + bf2f(ab2[2]));
    float rc = dc + bf2f(cb2[0]);
    if (*mode){
      float* o = (float*)out;
      o[(long)gr*3 + 0] = r0; o[(long)gr*3 + 1] = r1; o[(long)gr*3 + 2] = r2;
      o[(long)3*N + gr] = rc;
    } else {
      u16* o = (u16*)out;
      o[(long)gr*3 + 0] = f2bf(r0); o[(long)gr*3 + 1] = f2bf(r1);
      o[(long)gr*3 + 2] = f2bf(r2);
      o[(long)3*N + gr] = f2bf(rc);
    }
  }
}

extern "C" void kernel_launch(void* const* d_in, const int* in_sizes, int n_in,
                              void* d_out, int out_size, void* d_ws, size_t ws_size,
                              hipStream_t stream)
{
  const void* state = d_in[0];
  const void* h0    = d_in[1];
  const void* c0    = d_in[2];
  const int*  lens  = (const int*)d_in[3];
  const void* Wih   = d_in[4];
  const void* Whh   = d_in[5];
  const void* bih   = d_in[6];
  const void* bhh   = d_in[7];
  const void* aw0   = d_in[8];
  const void* ab0   = d_in[9];
  const void* aw1   = d_in[10];
  const void* ab1   = d_in[11];
  const void* aw2   = d_in[12];
  const void* ab2   = d_in[13];
  const void* cw0   = d_in[14];
  const void* cb0   = d_in[15];
  const void* cw1   = d_in[16];
  const void* cb1   = d_in[17];
  const void* cw2   = d_in[18];
  const void* cb2   = d_in[19];
  (void)in_sizes; (void)n_in;

  const int N = out_size / 4;             // actor 3N + critic N
  const int Np128 = (N + 127) & ~127;

  char* ws = (char*)d_ws;
  size_t cur = 0;
  auto alloc = [&](size_t bytes)->char*{
    char* p = ws + cur; cur += (bytes + 255) & ~(size_t)255; return p;
  };
  int* mode   = (int*)alloc(4);
  int* off    = (int*)alloc(129*4);
  int* tags   = (int*)alloc(8*256*4);
  u16* hbuf   = (u16*)alloc((size_t)2*BATCH*HDIM*2);
  u16* cbf    = (u16*)alloc((size_t)BATCH*HDIM*2);
  u16* wih_b  = (u16*)alloc((size_t)2048*256*2);
  u16* whh_b  = (u16*)alloc((size_t)2048*512*2);
  u16* bih_b  = (u16*)alloc(2048*2);
  u16* bhh_b  = (u16*)alloc(2048*2);
  u16* st_bf  = (u16*)alloc((size_t)T_STEPS*BATCH*DDIM*2);
  u16* wa0    = (u16*)alloc((size_t)512*768*2);
  u16* ba0    = (u16*)alloc(512*2);
  u16* wa1    = (u16*)alloc((size_t)512*512*2);
  u16* ba1    = (u16*)alloc(512*2);
  u16* wa2    = (u16*)alloc(1536*2);
  u16* ba2    = (u16*)alloc(256*2);
  u16* wc0    = (u16*)alloc((size_t)512*768*2);
  u16* bc0    = (u16*)alloc(512*2);
  u16* wc1    = (u16*)alloc((size_t)512*512*2);
  u16* bc1    = (u16*)alloc(512*2);
  u16* wc2    = (u16*)alloc(512*2);
  u16* bc2    = (u16*)alloc(256*2);
  u16* inp    = (u16*)alloc((size_t)Np128*768*2);

  sniff_kernel<<<1, 64, 0, stream>>>((const u16*)bih, mode);

  if (cur > ws_size){
    zero_out_kernel<<<(out_size + 255)/256, 256, 0, stream>>>(d_out, out_size, mode);
    return;
  }
  size_t rem = ws_size - cur;
  long CH_l = (long)((rem / 3) / (512*2)) & ~127L;
  int CH = (int)(CH_l > 8192 ? 8192 : CH_l);
  if (CH < 128){
    zero_out_kernel<<<(out_size + 255)/256, 256, 0, stream>>>(d_out, out_size, mode);
    return;
  }
  u16* bufA = (u16*)alloc((size_t)CH*512*2);
  u16* bufB = (u16*)alloc((size_t)CH*512*2);
  u16* bufC = (u16*)alloc((size_t)CH*512*2);

  auto cvt = [&](const void* src, u16* dst, int n){
    int thr = (n + 7) / 8;
    cvt_kernel<<<(thr + 255)/256, 256, 0, stream>>>(src, dst, n, mode);
  };
  cvt(Wih, wih_b, 2048*256);
  cvt(Whh, whh_b, 2048*512);
  cvt(bih, bih_b, 2048);
  cvt(bhh, bhh_b, 2048);
  cvt(h0,  hbuf + BATCH*HDIM, BATCH*HDIM);   // parity 1 = h_{-1}
  cvt(c0,  cbf, BATCH*HDIM);
  cvt(state, st_bf, T_STEPS*BATCH*DDIM);
  cvt(aw0, wa0, 512*768);  cvt(ab0, ba0, 512);
  cvt(aw1, wa1, 512*512);  cvt(ab1, ba1, 512);
  cvt(aw2, wa2, 1536);     cvt(ab2, ba2, 3);
  cvt(cw0, wc0, 512*768);  cvt(cb0, bc0, 512);
  cvt(cw1, wc1, 512*512);  cvt(cb1, bc1, 512);
  cvt(cw2, wc2, 512);      cvt(cb2, bc2, 1);

  hipMemsetAsync(tags, 0, 8*256*4, stream);
  scan_kernel<<<1, 64, 0, stream>>>(lens, off);
  pack_state_kernel<<<(T_STEPS*BATCH)/4, 256, 0, stream>>>(st_bf, lens, off, inp);

  lstm_kernel<<<128, 512, 0, stream>>>(whh_b, wih_b, bih_b, bhh_b, cbf, st_bf,
                                       hbuf, inp, off, lens, tags);

  for (int cs = 0; cs < Np128; cs += CH){
    int rows = (Np128 - cs) < CH ? (Np128 - cs) : CH;
    int gm = rows / 128;
    dim3 gg(gm, 4);
    gemm_kernel<<<gg, 256, 0, stream>>>(inp + (long)cs*768, wa0, ba0, bufA, 768);
    gemm_kernel<<<gg, 256, 0, stream>>>(bufA,               wa1, ba1, bufB, 512);
    gemm_kernel<<<gg, 256, 0, stream>>>(inp + (long)cs*768, wc0, bc0, bufA, 768);
    gemm_kernel<<<gg, 256, 0, stream>>>(bufA,               wc1, bc1, bufC, 512);
    int nvalid = (N - cs) < rows ? (N - cs) : rows;
    if (nvalid > 0)
      final_kernel<<<(nvalid + 3)/4, 256, 0, stream>>>(bufB, bufC, wa2, ba2,
                                                       wc2, bc2, d_out, cs,
                                                       nvalid, N, mode);
  }
}